// Round 2
// baseline (2883.992 us; speedup 1.0000x reference)
//
#include <hip/hip_runtime.h>

#define TLEN  512
#define HID   128
#define RSLOT 16   // ring slots per slice (power of 2)

typedef __attribute__((ext_vector_type(8))) short          bf16x8;
typedef __attribute__((ext_vector_type(4))) float          f32x4;
typedef __attribute__((ext_vector_type(4))) unsigned short u16x4;
typedef unsigned long long u64;

__device__ __forceinline__ unsigned short f2bf(float f) {
    union { float f; unsigned u; } v; v.f = f;
    unsigned r = v.u + 0x7fffu + ((v.u >> 16) & 1u);   // RNE
    return (unsigned short)(r >> 16);
}

__device__ __forceinline__ float fast_sigmoid(float x) {
    float e = __expf(-x);
    return __builtin_amdgcn_rcpf(1.0f + e);
}
__device__ __forceinline__ float fast_tanh(float x) {
    float ax = __builtin_fabsf(x);
    float e  = __expf(-2.0f * ax);
    float r  = (1.0f - e) * __builtin_amdgcn_rcpf(1.0f + e);
    return __builtin_copysignf(r, x);
}

__device__ __forceinline__ void poll_ge(const int* f, int v) {
    while (__hip_atomic_load(f, __ATOMIC_RELAXED, __HIP_MEMORY_SCOPE_AGENT) < v)
        __builtin_amdgcn_s_sleep(2);
}

// One LSTM layer over T steps for a 16-row batch slice.
// MODE 0: x from global floats (Din=6 padded to 32, K=160, NKT=5)
// MODE 1: x = prev layer h via ring  (Din=128, K=256, NKT=8)
// CONS: consume ring_in (poll pin_flag, publish cout_flag)
// PROD: produce ring_out (publish pout_flag, backpressure on cin_flag)
//
// Ring entry e = 2048 bf16 (4 KB) in A-fragment order == producer h-region
// order == consumer x-region order: elem (j,m) -> (j>>5)*512 +
// (((j&31)>>3)*16+m)*8 + (j&7). 8 B per thread, fully coalesced.
template<int MODE, bool CONS, bool PROD, bool WFC>
__device__ __forceinline__ void run_layer_p(
    const float* __restrict__ xin,
    const u64* __restrict__ rin, u64* __restrict__ rout,
    const int* pin_flag, int* cout_flag, const int* cin_flag, int* pout_flag,
    const float* __restrict__ wih, const float* __restrict__ whh,
    const float* __restrict__ bih, const float* __restrict__ bhh,
    unsigned short (* __restrict__ Abuf)[8 * 512],
    float* __restrict__ fcred,
    const int tid, const int wave, const int lane,
    const int n16, const int quad, const int bbase)
{
    constexpr int NKT  = MODE ? 8 : 5;     // K-tiles of 32
    constexpr int KX   = MODE ? 128 : 32;  // padded x-region width
    constexpr int DINL = MODE ? 128 : 6;   // real input features
    constexpr int HB0  = MODE ? 2048 : 512;// h-region start elem

    // ---- weights -> register-resident B fragments (bf16) ----
    bf16x8 Wf[4][NKT];
    float  bb[4];
#pragma unroll
    for (int g = 0; g < 4; ++g) {
        const int row = g * 128 + wave * 16 + n16;
        bb[g] = bih[row] + bhh[row];
#pragma unroll
        for (int kt = 0; kt < NKT; ++kt) {
            const int kbase = kt * 32 + quad * 8;
            bf16x8 wv;
#pragma unroll
            for (int j = 0; j < 8; ++j) {
                const int k = kbase + j;
                float f;
                if (k < KX) f = (k < DINL) ? wih[row * DINL + k] : 0.0f;
                else        f = whh[row * HID + (k - KX)];
                wv[j] = (short)f2bf(f);
            }
            Wf[g][kt] = wv;
        }
    }

    // ---- prologue: zero h-region; stage x(0) / entry 0 ----
    { u16x4 z = {0, 0, 0, 0}; *(u16x4*)&Abuf[0][HB0 + tid * 4] = z; }
    if constexpr (CONS) {
        poll_ge(pin_flag, 1);
        u64 v = __hip_atomic_load(rin + tid, __ATOMIC_RELAXED, __HIP_MEMORY_SCOPE_AGENT);
        *(u64*)&Abuf[0][tid * 4] = v;
    } else {
        const int m = tid >> 5, k = tid & 31;
        float v = (k < DINL) ? xin[((bbase + m) * TLEN + 0) * DINL + k] : 0.0f;
        Abuf[0][((k >> 3) * 16 + m) * 8 + (k & 7)] = f2bf(v);
    }

    float cst[4] = {0.f, 0.f, 0.f, 0.f};

    for (int t = 0; t < TLEN; ++t) {
        const int cur = t & 1, nxt = cur ^ 1;
        __syncthreads();   // Abuf[cur] ready; prior stores/loads drained (vmcnt(0))

        // ---- publish progress flags (thread 0) ----
        if (tid == 0) {
            if constexpr (CONS)  // entries <= t fully consumed
                __hip_atomic_store(cout_flag, t + 1, __ATOMIC_RELAXED, __HIP_MEMORY_SCOPE_AGENT);
            if constexpr (PROD)  // entries <= t-2 globally visible (drained by barrier)
                if (t >= 2)
                    __hip_atomic_store(pout_flag, t - 1, __ATOMIC_RELEASE, __HIP_MEMORY_SCOPE_AGENT);
        }

        // ---- producer: coalesced store of entry t-1 (h(t-1) in Abuf[cur]) ----
        if constexpr (PROD) {
            if (t >= 1) {
                const int e = t - 1;
                if (e >= RSLOT) poll_ge(cin_flag, e - RSLOT + 1);  // slot reuse backpressure
                u64 hv = *(const u64*)&Abuf[cur][HB0 + tid * 4];
                __hip_atomic_store(rout + (e & (RSLOT - 1)) * 512 + tid, hv,
                                   __ATOMIC_RELAXED, __HIP_MEMORY_SCOPE_AGENT);
            }
        }

        // ---- prefetch x(t+1) ----
        const bool has_next = (t + 1 < TLEN);
        u64 pf = 0; float pff = 0.0f;
        if (has_next) {
            if constexpr (CONS) {
                poll_ge(pin_flag, t + 2);
                pf = __hip_atomic_load(rin + ((t + 1) & (RSLOT - 1)) * 512 + tid,
                                       __ATOMIC_RELAXED, __HIP_MEMORY_SCOPE_AGENT);
            } else {
                const int m = tid >> 5, k = tid & 31;
                if (k < DINL) pff = xin[((bbase + m) * TLEN + (t + 1)) * DINL + k];
            }
        }

        // ---- gates = A @ W^T (fp32 accum) ----
        f32x4 acc[4];
#pragma unroll
        for (int g = 0; g < 4; ++g) { f32x4 z = {0.f, 0.f, 0.f, 0.f}; acc[g] = z; }
#pragma unroll
        for (int kt = 0; kt < NKT; ++kt) {
            bf16x8 a = *(const bf16x8*)&Abuf[cur][kt * 512 + lane * 8];
#pragma unroll
            for (int g = 0; g < 4; ++g)
                acc[g] = __builtin_amdgcn_mfma_f32_16x16x32_bf16(a, Wf[g][kt], acc[g], 0, 0, 0);
        }

        // ---- in-lane LSTM cell update ----
        unsigned short hb[4]; float hf[4];
#pragma unroll
        for (int r = 0; r < 4; ++r) {
            const float iv = fast_sigmoid(acc[0][r] + bb[0]);
            const float fv = fast_sigmoid(acc[1][r] + bb[1]);
            const float gv = fast_tanh  (acc[2][r] + bb[2]);
            const float ov = fast_sigmoid(acc[3][r] + bb[3]);
            const float c  = fv * cst[r] + iv * gv;
            cst[r] = c;
            const float h  = ov * fast_tanh(c);
            hf[r] = h;
            hb[r] = f2bf(h);
        }

        // ---- h -> Abuf[nxt] h-region (A-layout, for own recurrence) ----
        {
            const int j  = wave * 16 + n16;
            const int kh = KX + j;
            const int kt = kh >> 5, kk = kh & 31;
            const int eb = kt * 512 + (kk >> 3) * 128 + (kk & 7);
#pragma unroll
            for (int r = 0; r < 4; ++r)
                Abuf[nxt][eb + (quad * 4 + r) * 8] = hb[r];
        }
        if constexpr (WFC) {
            if (t == TLEN - 1)
#pragma unroll
                for (int r = 0; r < 4; ++r)
                    fcred[(quad * 4 + r) * HID + wave * 16 + n16] = hf[r];
        }

        // ---- commit prefetched x(t+1) into Abuf[nxt] x-region ----
        if (has_next) {
            if constexpr (CONS) {
                *(u64*)&Abuf[nxt][tid * 4] = pf;
            } else {
                const int m = tid >> 5, k = tid & 31;
                Abuf[nxt][((k >> 3) * 16 + m) * 8 + (k & 7)] = f2bf(pff);
            }
        }
    }

    // ---- producer epilogue: flush entry T-1 and final flags ----
    if constexpr (PROD) {
        __syncthreads();   // h(T-1) committed to Abuf[0]; step T-1 stores drained
        if (tid == 0)
            __hip_atomic_store(pout_flag, TLEN - 1, __ATOMIC_RELEASE, __HIP_MEMORY_SCOPE_AGENT);
        {
            const int e = TLEN - 1;
            if (e >= RSLOT) poll_ge(cin_flag, e - RSLOT + 1);
            u64 hv = *(const u64*)&Abuf[TLEN & 1][HB0 + tid * 4];
            __hip_atomic_store(rout + (e & (RSLOT - 1)) * 512 + tid, hv,
                               __ATOMIC_RELAXED, __HIP_MEMORY_SCOPE_AGENT);
        }
        __syncthreads();   // drain entry T-1 stores (vmcnt(0) before barrier)
        if (tid == 0)
            __hip_atomic_store(pout_flag, TLEN, __ATOMIC_RELEASE, __HIP_MEMORY_SCOPE_AGENT);
    }
}

extern "C" __global__ __launch_bounds__(512, 2)
void lstm3_pipe_kernel(const float* __restrict__ xin,
    const float* __restrict__ wih0, const float* __restrict__ whh0,
    const float* __restrict__ bih0, const float* __restrict__ bhh0,
    const float* __restrict__ wih1, const float* __restrict__ whh1,
    const float* __restrict__ bih1, const float* __restrict__ bhh1,
    const float* __restrict__ wih2, const float* __restrict__ whh2,
    const float* __restrict__ bih2, const float* __restrict__ bhh2,
    const float* __restrict__ fcw, const float* __restrict__ fcb,
    float* __restrict__ out,
    int* __restrict__ flags, u64* __restrict__ ring0, u64* __restrict__ ring1)
{
    __shared__ unsigned short Abuf[2][8 * 512];   // 16 KB
    __shared__ float fcred[16 * HID];             // 8 KB

    const int tid   = threadIdx.x;
    const int wave  = tid >> 6;
    const int lane  = tid & 63;
    const int n16   = lane & 15;
    const int quad  = lane >> 4;
    const int layer = blockIdx.x >> 6;
    const int slice = blockIdx.x & 63;
    const int bbase = slice * 16;

    u64* r0 = ring0 + (size_t)slice * (RSLOT * 512);
    u64* r1 = ring1 + (size_t)slice * (RSLOT * 512);
    int* prod0 = flags + 0   + slice;
    int* prod1 = flags + 64  + slice;
    int* cons1 = flags + 128 + slice;
    int* cons2 = flags + 192 + slice;

    if (layer == 0) {
        run_layer_p<0, false, true, false>(xin, nullptr, r0,
            nullptr, nullptr, cons1, prod0,
            wih0, whh0, bih0, bhh0, Abuf, fcred, tid, wave, lane, n16, quad, bbase);
    } else if (layer == 1) {
        run_layer_p<1, true, true, false>(nullptr, r0, r1,
            prod0, cons1, cons2, prod1,
            wih1, whh1, bih1, bhh1, Abuf, fcred, tid, wave, lane, n16, quad, bbase);
    } else {
        run_layer_p<1, true, false, true>(nullptr, r1, nullptr,
            prod1, cons2, nullptr, nullptr,
            wih2, whh2, bih2, bhh2, Abuf, fcred, tid, wave, lane, n16, quad, bbase);
        __syncthreads();
        if (tid < 16) {
            float s = 0.0f;
#pragma unroll 8
            for (int j = 0; j < HID; ++j) s += fcw[j] * fcred[tid * HID + j];
            out[bbase + tid] = s + fcb[0];
        }
    }
}

extern "C" void kernel_launch(void* const* d_in, const int* in_sizes, int n_in,
                              void* d_out, int out_size, void* d_ws, size_t ws_size,
                              hipStream_t stream) {
    (void)in_sizes; (void)n_in; (void)out_size; (void)ws_size;
    const float* x    = (const float*)d_in[0];
    const float* wih0 = (const float*)d_in[1];
    const float* whh0 = (const float*)d_in[2];
    const float* bih0 = (const float*)d_in[3];
    const float* bhh0 = (const float*)d_in[4];
    const float* wih1 = (const float*)d_in[5];
    const float* whh1 = (const float*)d_in[6];
    const float* bih1 = (const float*)d_in[7];
    const float* bhh1 = (const float*)d_in[8];
    const float* wih2 = (const float*)d_in[9];
    const float* whh2 = (const float*)d_in[10];
    const float* bih2 = (const float*)d_in[11];
    const float* bhh2 = (const float*)d_in[12];
    const float* fcw  = (const float*)d_in[13];
    const float* fcb  = (const float*)d_in[14];
    float* out = (float*)d_out;

    // ws layout: flags (4 KB; poison 0xAA.. is negative => "not ready", no init
    // needed), ring0 (64 slices x 16 slots x 4 KB = 4 MB), ring1 (4 MB).
    int* flags = (int*)d_ws;
    u64* ring0 = (u64*)((char*)d_ws + 4096);
    u64* ring1 = ring0 + (size_t)64 * RSLOT * 512;

    lstm3_pipe_kernel<<<dim3(192), dim3(512), 0, stream>>>(
        x, wih0, whh0, bih0, bhh0, wih1, whh1, bih1, bhh1,
        wih2, whh2, bih2, bhh2, fcw, fcb, out, flags, ring0, ring1);
}

// Round 3
// 1181.847 us; speedup vs baseline: 2.4402x; 2.4402x over previous
//
#include <hip/hip_runtime.h>

#define TLEN  512
#define HID   128
#define RSLOT 16   // ring slots per slice (power of 2)

typedef __attribute__((ext_vector_type(8))) short          bf16x8;
typedef __attribute__((ext_vector_type(4))) float          f32x4;
typedef __attribute__((ext_vector_type(4))) unsigned short u16x4;
typedef unsigned long long u64;

__device__ __forceinline__ unsigned short f2bf(float f) {
    union { float f; unsigned u; } v; v.f = f;
    unsigned r = v.u + 0x7fffu + ((v.u >> 16) & 1u);   // RNE
    return (unsigned short)(r >> 16);
}

__device__ __forceinline__ float fast_sigmoid(float x) {
    float e = __expf(-x);
    return __builtin_amdgcn_rcpf(1.0f + e);
}
__device__ __forceinline__ float fast_tanh(float x) {
    float ax = __builtin_fabsf(x);
    float e  = __expf(-2.0f * ax);
    float r  = (1.0f - e) * __builtin_amdgcn_rcpf(1.0f + e);
    return __builtin_copysignf(r, x);
}

// check-first poll: steady state = one agent load, no sleep
__device__ __forceinline__ void flag_wait(const int* f, int v) {
    int x = __hip_atomic_load(f, __ATOMIC_RELAXED, __HIP_MEMORY_SCOPE_AGENT);
    while (x < v) {
        __builtin_amdgcn_s_sleep(8);
        x = __hip_atomic_load(f, __ATOMIC_RELAXED, __HIP_MEMORY_SCOPE_AGENT);
    }
}

// One LSTM layer over T steps for a 16-row batch slice.
// MODE 0: x from global floats (Din=6 padded to 32, K=160, NKT=5)
// MODE 1: x = prev layer h via ring  (Din=128, K=256, NKT=8)
// Ring entry e = 2048 bf16 (4 KB) in A-fragment order (== producer h-region
// order == consumer x-region order). 8 B per thread, coalesced.
// Consumer runs prefetch-distance-2: at step t it loads entry t+2 (pfB) and
// commits entry t+1 (pfA, loaded last step) into Abuf[nxt].
template<int MODE, bool CONS, bool PROD, bool WFC>
__device__ __forceinline__ void run_layer_p(
    const float* __restrict__ xin,
    const u64* __restrict__ rin, u64* __restrict__ rout,
    const int* pin_flag, int* cout_flag, const int* cin_flag, int* pout_flag,
    const float* __restrict__ wih, const float* __restrict__ whh,
    const float* __restrict__ bih, const float* __restrict__ bhh,
    unsigned short (* __restrict__ Abuf)[8 * 512],
    float* __restrict__ fcred,
    const int tid, const int wave, const int lane,
    const int n16, const int quad, const int bbase)
{
    constexpr int NKT  = MODE ? 8 : 5;     // K-tiles of 32
    constexpr int KX   = MODE ? 128 : 32;  // padded x-region width
    constexpr int DINL = MODE ? 128 : 6;   // real input features
    constexpr int HB0  = MODE ? 2048 : 512;// h-region start elem

    // ---- weights -> register-resident B fragments (bf16) ----
    bf16x8 Wf[4][NKT];
    float  bb[4];
#pragma unroll
    for (int g = 0; g < 4; ++g) {
        const int row = g * 128 + wave * 16 + n16;
        bb[g] = bih[row] + bhh[row];
#pragma unroll
        for (int kt = 0; kt < NKT; ++kt) {
            const int kbase = kt * 32 + quad * 8;
            bf16x8 wv;
#pragma unroll
            for (int j = 0; j < 8; ++j) {
                const int k = kbase + j;
                float f;
                if (k < KX) f = (k < DINL) ? wih[row * DINL + k] : 0.0f;
                else        f = whh[row * HID + (k - KX)];
                wv[j] = (short)f2bf(f);
            }
            Wf[g][kt] = wv;
        }
    }

    // ---- prologue: zero h-region; stage entry 0 -> Abuf[0], entry 1 -> pfA ----
    { u16x4 z = {0, 0, 0, 0}; *(u16x4*)&Abuf[0][HB0 + tid * 4] = z; }
    u64 pfA = 0;
    if constexpr (CONS) {
        flag_wait(pin_flag, 1);
        u64 v = __hip_atomic_load(rin + tid, __ATOMIC_RELAXED, __HIP_MEMORY_SCOPE_AGENT);
        *(u64*)&Abuf[0][tid * 4] = v;
        flag_wait(pin_flag, 2);
        pfA = __hip_atomic_load(rin + 512 + tid, __ATOMIC_RELAXED, __HIP_MEMORY_SCOPE_AGENT);
    } else {
        const int m = tid >> 5, k = tid & 31;
        float v = (k < DINL) ? xin[((bbase + m) * TLEN + 0) * DINL + k] : 0.0f;
        Abuf[0][((k >> 3) * 16 + m) * 8 + (k & 7)] = f2bf(v);
    }

    float cst[4] = {0.f, 0.f, 0.f, 0.f};

    for (int t = 0; t < TLEN; ++t) {
        const int cur = t & 1, nxt = cur ^ 1;
        __syncthreads();   // Abuf[cur] ready; every wave's stores drained (vmcnt(0))

        // ---- publish progress (tid 0; barrier already drained all stores) ----
        if (tid == 0) {
            if constexpr (CONS)  // entries <= t+1 are in regs/LDS: slots reusable
                __hip_atomic_store(cout_flag, t + 2, __ATOMIC_RELAXED, __HIP_MEMORY_SCOPE_AGENT);
            if constexpr (PROD)  // entries <= t-2 globally visible
                if (t >= 2)
                    __hip_atomic_store(pout_flag, t - 1, __ATOMIC_RELAXED, __HIP_MEMORY_SCOPE_AGENT);
        }

        // ---- producer: coalesced store of entry t-1 (h(t-1) in Abuf[cur]) ----
        if constexpr (PROD) {
            if (t >= 1) {
                const int e = t - 1;
                if (e >= RSLOT) flag_wait(cin_flag, e - RSLOT + 1);  // slot reuse
                u64 hv = *(const u64*)&Abuf[cur][HB0 + tid * 4];
                __hip_atomic_store(rout + (e & (RSLOT - 1)) * 512 + tid, hv,
                                   __ATOMIC_RELAXED, __HIP_MEMORY_SCOPE_AGENT);
            }
        }

        // ---- prefetch: ring entry t+2 / global x(t+1) ----
        u64 pfB = 0; float pff = 0.0f;
        if constexpr (CONS) {
            if (t + 2 < TLEN) {
                flag_wait(pin_flag, t + 3);
                pfB = __hip_atomic_load(rin + ((t + 2) & (RSLOT - 1)) * 512 + tid,
                                        __ATOMIC_RELAXED, __HIP_MEMORY_SCOPE_AGENT);
            }
        } else {
            if (t + 1 < TLEN) {
                const int m = tid >> 5, k = tid & 31;
                if (k < DINL) pff = xin[((bbase + m) * TLEN + (t + 1)) * DINL + k];
            }
        }

        // ---- gates = A @ W^T (fp32 accum) ----
        f32x4 acc[4];
#pragma unroll
        for (int g = 0; g < 4; ++g) { f32x4 z = {0.f, 0.f, 0.f, 0.f}; acc[g] = z; }
#pragma unroll
        for (int kt = 0; kt < NKT; ++kt) {
            bf16x8 a = *(const bf16x8*)&Abuf[cur][kt * 512 + lane * 8];
#pragma unroll
            for (int g = 0; g < 4; ++g)
                acc[g] = __builtin_amdgcn_mfma_f32_16x16x32_bf16(a, Wf[g][kt], acc[g], 0, 0, 0);
        }

        // ---- in-lane LSTM cell update ----
        unsigned short hb[4]; float hf[4];
#pragma unroll
        for (int r = 0; r < 4; ++r) {
            const float iv = fast_sigmoid(acc[0][r] + bb[0]);
            const float fv = fast_sigmoid(acc[1][r] + bb[1]);
            const float gv = fast_tanh  (acc[2][r] + bb[2]);
            const float ov = fast_sigmoid(acc[3][r] + bb[3]);
            const float c  = fv * cst[r] + iv * gv;
            cst[r] = c;
            const float h  = ov * fast_tanh(c);
            hf[r] = h;
            hb[r] = f2bf(h);
        }

        // ---- h -> Abuf[nxt] h-region (A-layout, own recurrence) ----
        {
            const int j  = wave * 16 + n16;
            const int kh = KX + j;
            const int kt = kh >> 5, kk = kh & 31;
            const int eb = kt * 512 + (kk >> 3) * 128 + (kk & 7);
#pragma unroll
            for (int r = 0; r < 4; ++r)
                Abuf[nxt][eb + (quad * 4 + r) * 8] = hb[r];
        }
        if constexpr (WFC) {
            if (t == TLEN - 1)
#pragma unroll
                for (int r = 0; r < 4; ++r)
                    fcred[(quad * 4 + r) * HID + wave * 16 + n16] = hf[r];
        }

        // ---- commit next-step x into Abuf[nxt] x-region ----
        if (t + 1 < TLEN) {
            if constexpr (CONS) {
                *(u64*)&Abuf[nxt][tid * 4] = pfA;   // entry t+1 (loaded last step)
                pfA = pfB;
            } else {
                const int m = tid >> 5, k = tid & 31;
                Abuf[nxt][((k >> 3) * 16 + m) * 8 + (k & 7)] = f2bf(pff);
            }
        }
    }

    // ---- producer epilogue: flush entry T-1, final flags ----
    if constexpr (PROD) {
        __syncthreads();   // h(T-1) committed to Abuf; step T-1 stores drained
        if (tid == 0)
            __hip_atomic_store(pout_flag, TLEN - 1, __ATOMIC_RELAXED, __HIP_MEMORY_SCOPE_AGENT);
        {
            const int e = TLEN - 1;
            if (e >= RSLOT) flag_wait(cin_flag, e - RSLOT + 1);
            u64 hv = *(const u64*)&Abuf[TLEN & 1][HB0 + tid * 4];
            __hip_atomic_store(rout + (e & (RSLOT - 1)) * 512 + tid, hv,
                               __ATOMIC_RELAXED, __HIP_MEMORY_SCOPE_AGENT);
        }
        __syncthreads();   // drain entry T-1 stores
        if (tid == 0)
            __hip_atomic_store(pout_flag, TLEN, __ATOMIC_RELAXED, __HIP_MEMORY_SCOPE_AGENT);
    }
}

extern "C" __global__ __launch_bounds__(512, 2)
void lstm3_pipe_kernel(const float* __restrict__ xin,
    const float* __restrict__ wih0, const float* __restrict__ whh0,
    const float* __restrict__ bih0, const float* __restrict__ bhh0,
    const float* __restrict__ wih1, const float* __restrict__ whh1,
    const float* __restrict__ bih1, const float* __restrict__ bhh1,
    const float* __restrict__ wih2, const float* __restrict__ whh2,
    const float* __restrict__ bih2, const float* __restrict__ bhh2,
    const float* __restrict__ fcw, const float* __restrict__ fcb,
    float* __restrict__ out,
    int* __restrict__ flags, u64* __restrict__ ring0, u64* __restrict__ ring1)
{
    __shared__ unsigned short Abuf[2][8 * 512];   // 16 KB
    __shared__ float fcred[16 * HID];             // 8 KB

    const int tid   = threadIdx.x;
    const int wave  = tid >> 6;
    const int lane  = tid & 63;
    const int n16   = lane & 15;
    const int quad  = lane >> 4;
    const int layer = blockIdx.x >> 6;
    const int slice = blockIdx.x & 63;
    const int bbase = slice * 16;

    u64* r0 = ring0 + (size_t)slice * (RSLOT * 512);
    u64* r1 = ring1 + (size_t)slice * (RSLOT * 512);
    // each flag on its own 256 B line: kind*64 + slice, stride 64 ints
    int* prod0 = flags + (size_t)(0 * 64 + slice) * 64;
    int* prod1 = flags + (size_t)(1 * 64 + slice) * 64;
    int* cons1 = flags + (size_t)(2 * 64 + slice) * 64;
    int* cons2 = flags + (size_t)(3 * 64 + slice) * 64;

    if (layer == 0) {
        run_layer_p<0, false, true, false>(xin, nullptr, r0,
            nullptr, nullptr, cons1, prod0,
            wih0, whh0, bih0, bhh0, Abuf, fcred, tid, wave, lane, n16, quad, bbase);
    } else if (layer == 1) {
        run_layer_p<1, true, true, false>(nullptr, r0, r1,
            prod0, cons1, cons2, prod1,
            wih1, whh1, bih1, bhh1, Abuf, fcred, tid, wave, lane, n16, quad, bbase);
    } else {
        run_layer_p<1, true, false, true>(nullptr, r1, nullptr,
            prod1, cons2, nullptr, nullptr,
            wih2, whh2, bih2, bhh2, Abuf, fcred, tid, wave, lane, n16, quad, bbase);
        __syncthreads();
        if (tid < 16) {
            float s = 0.0f;
#pragma unroll 8
            for (int j = 0; j < HID; ++j) s += fcw[j] * fcred[tid * HID + j];
            out[bbase + tid] = s + fcb[0];
        }
    }
}

extern "C" void kernel_launch(void* const* d_in, const int* in_sizes, int n_in,
                              void* d_out, int out_size, void* d_ws, size_t ws_size,
                              hipStream_t stream) {
    (void)in_sizes; (void)n_in; (void)out_size; (void)ws_size;
    const float* x    = (const float*)d_in[0];
    const float* wih0 = (const float*)d_in[1];
    const float* whh0 = (const float*)d_in[2];
    const float* bih0 = (const float*)d_in[3];
    const float* bhh0 = (const float*)d_in[4];
    const float* wih1 = (const float*)d_in[5];
    const float* whh1 = (const float*)d_in[6];
    const float* bih1 = (const float*)d_in[7];
    const float* bhh1 = (const float*)d_in[8];
    const float* wih2 = (const float*)d_in[9];
    const float* whh2 = (const float*)d_in[10];
    const float* bih2 = (const float*)d_in[11];
    const float* bhh2 = (const float*)d_in[12];
    const float* fcw  = (const float*)d_in[13];
    const float* fcb  = (const float*)d_in[14];
    float* out = (float*)d_out;

    // ws layout: flags 64 KB (4 kinds x 64 slices x 256 B; poison 0xAA.. is
    // negative => "not ready", no init needed), ring0 4 MB, ring1 4 MB.
    int* flags = (int*)d_ws;
    u64* ring0 = (u64*)((char*)d_ws + 65536);
    u64* ring1 = ring0 + (size_t)64 * RSLOT * 512;

    lstm3_pipe_kernel<<<dim3(192), dim3(512), 0, stream>>>(
        x, wih0, whh0, bih0, bhh0, wih1, whh1, bih1, bhh1,
        wih2, whh2, bih2, bhh2, fcw, fcb, out, flags, ring0, ring1);
}

// Round 4
// 1061.581 us; speedup vs baseline: 2.7167x; 1.1133x over previous
//
#include <hip/hip_runtime.h>

#define TLEN  512
#define HID   128
#define RSLOT 32   // ring slots per slice (power of 2)

typedef __attribute__((ext_vector_type(8))) short          bf16x8;
typedef __attribute__((ext_vector_type(4))) float          f32x4;
typedef __attribute__((ext_vector_type(4))) unsigned short u16x4;
typedef unsigned long long u64;

#define LOG2E 1.4426950408889634f

__device__ __forceinline__ unsigned short f2bf(float f) {
    union { float f; unsigned u; } v; v.f = f;
    unsigned r = v.u + 0x7fffu + ((v.u >> 16) & 1u);   // RNE
    return (unsigned short)(r >> 16);
}

// xs pre-scaled by log2(e): sigmoid(x_true)
__device__ __forceinline__ float sig_ps(float xs) {
    return __builtin_amdgcn_rcpf(1.0f + __builtin_exp2f(-xs));
}
// xs pre-scaled by 2*log2(e): tanh(x_true)
__device__ __forceinline__ float tanh_ps(float xs) {
    float e = __builtin_exp2f(-__builtin_fabsf(xs));
    float r = (1.0f - e) * __builtin_amdgcn_rcpf(1.0f + e);
    return __builtin_copysignf(r, xs);
}

// check-first poll: steady state = one agent load, no sleep
__device__ __forceinline__ void flag_wait(const int* f, int v) {
    int x = __hip_atomic_load(f, __ATOMIC_RELAXED, __HIP_MEMORY_SCOPE_AGENT);
    while (x < v) {
        __builtin_amdgcn_s_sleep(8);
        x = __hip_atomic_load(f, __ATOMIC_RELAXED, __HIP_MEMORY_SCOPE_AGENT);
    }
}

// One LSTM layer over T steps for a 16-row batch slice.
// MODE 0: x from global floats (Din=6 padded to 32, K=160, NKT=5)
// MODE 1: x = prev layer h via ring  (Din=128, K=256, NKT=8)
// Ring entry e = 2048 bf16 (4 KB) in A-fragment order (== producer h-region
// order == consumer x-region order). 8 B per thread, coalesced.
// Consumer: distance-4 register queue. At step t: poll flag for entry t+4,
// issue its load into q3; commit q0 (entry t+1, loaded 3 steps ago, drained
// by an intervening barrier's vmcnt(0)) into Abuf[nxt]; shift queue.
template<int MODE, bool CONS, bool PROD, bool WFC>
__device__ __forceinline__ void run_layer_p(
    const float* __restrict__ xin,
    const u64* __restrict__ rin, u64* __restrict__ rout,
    const int* pin_flag, int* cout_flag, const int* cin_flag, int* pout_flag,
    const float* __restrict__ wih, const float* __restrict__ whh,
    const float* __restrict__ bih, const float* __restrict__ bhh,
    unsigned short (* __restrict__ Abuf)[8 * 512],
    float* __restrict__ fcred,
    const int tid, const int wave, const int lane,
    const int n16, const int quad, const int bbase)
{
    constexpr int NKT  = MODE ? 8 : 5;     // K-tiles of 32
    constexpr int KX   = MODE ? 128 : 32;  // padded x-region width
    constexpr int DINL = MODE ? 128 : 6;   // real input features
    constexpr int HB0  = MODE ? 2048 : 512;// h-region start elem

    // ---- weights -> register-resident B fragments (bf16), activation-prescaled ----
    bf16x8 Wf[4][NKT];
    float  bb[4];
#pragma unroll
    for (int g = 0; g < 4; ++g) {
        const float sc = (g == 2) ? 2.0f * LOG2E : LOG2E;  // tanh gate gets 2*log2e
        const int row = g * 128 + wave * 16 + n16;
        bb[g] = (bih[row] + bhh[row]) * sc;
#pragma unroll
        for (int kt = 0; kt < NKT; ++kt) {
            const int kbase = kt * 32 + quad * 8;
            bf16x8 wv;
#pragma unroll
            for (int j = 0; j < 8; ++j) {
                const int k = kbase + j;
                float f;
                if (k < KX) f = (k < DINL) ? wih[row * DINL + k] : 0.0f;
                else        f = whh[row * HID + (k - KX)];
                wv[j] = (short)f2bf(f * sc);
            }
            Wf[g][kt] = wv;
        }
    }

    // ---- prologue: zero h-region; stage entry 0 -> LDS, entries 1..3 -> queue ----
    { u16x4 z = {0, 0, 0, 0}; *(u16x4*)&Abuf[0][HB0 + tid * 4] = z; }
    u64 q0 = 0, q1 = 0, q2 = 0, q3 = 0;
    float pfx0 = 0.0f;
    if constexpr (CONS) {
        flag_wait(pin_flag, 1);
        u64 v0 = __hip_atomic_load(rin + tid, __ATOMIC_RELAXED, __HIP_MEMORY_SCOPE_AGENT);
        *(u64*)&Abuf[0][tid * 4] = v0;
        flag_wait(pin_flag, 4);
        q0 = __hip_atomic_load(rin + 1 * 512 + tid, __ATOMIC_RELAXED, __HIP_MEMORY_SCOPE_AGENT);
        q1 = __hip_atomic_load(rin + 2 * 512 + tid, __ATOMIC_RELAXED, __HIP_MEMORY_SCOPE_AGENT);
        q2 = __hip_atomic_load(rin + 3 * 512 + tid, __ATOMIC_RELAXED, __HIP_MEMORY_SCOPE_AGENT);
    } else {
        const int m = tid >> 5, k = tid & 31;
        float v = (k < DINL) ? xin[((bbase + m) * TLEN + 0) * DINL + k] : 0.0f;
        Abuf[0][((k >> 3) * 16 + m) * 8 + (k & 7)] = f2bf(v);
        if (k < DINL) pfx0 = xin[((bbase + m) * TLEN + 1) * DINL + k];
    }

    float cst[4] = {0.f, 0.f, 0.f, 0.f};

    for (int t = 0; t < TLEN; ++t) {
        const int cur = t & 1, nxt = cur ^ 1;
        __syncthreads();   // Abuf[cur] ready; all waves' vmem drained (vmcnt(0))

        // ---- publish progress (tid 0). Barrier drained all loads/stores:
        //  - CONS: entries <= t+3 are complete in regs/LDS -> slots free
        //  - PROD: entries <= t-2 stores drained -> globally visible
        if (tid == 0) {
            if constexpr (CONS)
                __hip_atomic_store(cout_flag, t + 4, __ATOMIC_RELAXED, __HIP_MEMORY_SCOPE_AGENT);
            if constexpr (PROD)
                if (t >= 2)
                    __hip_atomic_store(pout_flag, t - 1, __ATOMIC_RELAXED, __HIP_MEMORY_SCOPE_AGENT);
        }

        // ---- producer: coalesced store of entry t-1 (h(t-1) in Abuf[cur]) ----
        if constexpr (PROD) {
            if (t >= 1) {
                const int e = t - 1;
                // batched slot-reuse check for entries e..e+3 (1-in-4 steps)
                if ((e & 3) == 0 && e + 4 > RSLOT) flag_wait(cin_flag, e + 4 - RSLOT);
                u64 hv = *(const u64*)&Abuf[cur][HB0 + tid * 4];
                __hip_atomic_store(rout + (e & (RSLOT - 1)) * 512 + tid, hv,
                                   __ATOMIC_RELAXED, __HIP_MEMORY_SCOPE_AGENT);
            }
        }

        // ---- prefetch: ring entry t+4 / global x(t+2) ----
        float pfx1 = 0.0f;
        if constexpr (CONS) {
            if (t + 4 < TLEN) {
                flag_wait(pin_flag, t + 5);
                q3 = __hip_atomic_load(rin + ((t + 4) & (RSLOT - 1)) * 512 + tid,
                                       __ATOMIC_RELAXED, __HIP_MEMORY_SCOPE_AGENT);
            }
        } else {
            if (t + 2 < TLEN) {
                const int m = tid >> 5, k = tid & 31;
                if (k < DINL) pfx1 = xin[((bbase + m) * TLEN + (t + 2)) * DINL + k];
            }
        }

        // ---- gates = A @ W^T (fp32 accum) ----
        f32x4 acc[4];
#pragma unroll
        for (int g = 0; g < 4; ++g) { f32x4 z = {0.f, 0.f, 0.f, 0.f}; acc[g] = z; }
#pragma unroll
        for (int kt = 0; kt < NKT; ++kt) {
            bf16x8 a = *(const bf16x8*)&Abuf[cur][kt * 512 + lane * 8];
#pragma unroll
            for (int g = 0; g < 4; ++g)
                acc[g] = __builtin_amdgcn_mfma_f32_16x16x32_bf16(a, Wf[g][kt], acc[g], 0, 0, 0);
        }

        // ---- in-lane LSTM cell update (pre-scaled gates) ----
        unsigned short hb[4]; float hf[4];
#pragma unroll
        for (int r = 0; r < 4; ++r) {
            const float iv = sig_ps (acc[0][r] + bb[0]);
            const float fv = sig_ps (acc[1][r] + bb[1]);
            const float gv = tanh_ps(acc[2][r] + bb[2]);
            const float ov = sig_ps (acc[3][r] + bb[3]);
            const float c  = fv * cst[r] + iv * gv;
            cst[r] = c;
            const float h  = ov * tanh_ps(c * (2.0f * LOG2E));
            hf[r] = h;
            hb[r] = f2bf(h);
        }

        // ---- h -> Abuf[nxt] h-region (A-layout, own recurrence) ----
        {
            const int j  = wave * 16 + n16;
            const int kh = KX + j;
            const int kt = kh >> 5, kk = kh & 31;
            const int eb = kt * 512 + (kk >> 3) * 128 + (kk & 7);
#pragma unroll
            for (int r = 0; r < 4; ++r)
                Abuf[nxt][eb + (quad * 4 + r) * 8] = hb[r];
        }
        if constexpr (WFC) {
            if (t == TLEN - 1)
#pragma unroll
                for (int r = 0; r < 4; ++r)
                    fcred[(quad * 4 + r) * HID + wave * 16 + n16] = hf[r];
        }

        // ---- commit next-step x into Abuf[nxt] x-region; shift queues ----
        if (t + 1 < TLEN) {
            if constexpr (CONS) {
                *(u64*)&Abuf[nxt][tid * 4] = q0;   // entry t+1
                q0 = q1; q1 = q2; q2 = q3;
            } else {
                const int m = tid >> 5, k = tid & 31;
                Abuf[nxt][((k >> 3) * 16 + m) * 8 + (k & 7)] = f2bf(pfx0);
                pfx0 = pfx1;
            }
        }
    }

    // ---- producer epilogue: flush entry T-1, final flags ----
    if constexpr (PROD) {
        __syncthreads();   // h(T-1) in Abuf[0]; step T-1 stores drained
        if (tid == 0)
            __hip_atomic_store(pout_flag, TLEN - 1, __ATOMIC_RELAXED, __HIP_MEMORY_SCOPE_AGENT);
        {
            u64 hv = *(const u64*)&Abuf[TLEN & 1][HB0 + tid * 4];
            __hip_atomic_store(rout + ((TLEN - 1) & (RSLOT - 1)) * 512 + tid, hv,
                               __ATOMIC_RELAXED, __HIP_MEMORY_SCOPE_AGENT);
        }
        __syncthreads();   // drain entry T-1 stores
        if (tid == 0)
            __hip_atomic_store(pout_flag, TLEN, __ATOMIC_RELAXED, __HIP_MEMORY_SCOPE_AGENT);
    }
}

extern "C" __global__ __launch_bounds__(512, 2)
void lstm3_pipe_kernel(const float* __restrict__ xin,
    const float* __restrict__ wih0, const float* __restrict__ whh0,
    const float* __restrict__ bih0, const float* __restrict__ bhh0,
    const float* __restrict__ wih1, const float* __restrict__ whh1,
    const float* __restrict__ bih1, const float* __restrict__ bhh1,
    const float* __restrict__ wih2, const float* __restrict__ whh2,
    const float* __restrict__ bih2, const float* __restrict__ bhh2,
    const float* __restrict__ fcw, const float* __restrict__ fcb,
    float* __restrict__ out,
    int* __restrict__ flags, u64* __restrict__ ring0, u64* __restrict__ ring1)
{
    __shared__ unsigned short Abuf[2][8 * 512];   // 16 KB
    __shared__ float fcred[16 * HID];             // 8 KB

    const int tid   = threadIdx.x;
    const int wave  = tid >> 6;
    const int lane  = tid & 63;
    const int n16   = lane & 15;
    const int quad  = lane >> 4;
    const int layer = blockIdx.x >> 6;
    const int slice = blockIdx.x & 63;
    const int bbase = slice * 16;

    u64* r0 = ring0 + (size_t)slice * (RSLOT * 512);
    u64* r1 = ring1 + (size_t)slice * (RSLOT * 512);
    // each flag on its own 256 B line: kind*64 + slice, stride 64 ints
    int* prod0 = flags + (size_t)(0 * 64 + slice) * 64;
    int* prod1 = flags + (size_t)(1 * 64 + slice) * 64;
    int* cons1 = flags + (size_t)(2 * 64 + slice) * 64;
    int* cons2 = flags + (size_t)(3 * 64 + slice) * 64;

    if (layer == 0) {
        run_layer_p<0, false, true, false>(xin, nullptr, r0,
            nullptr, nullptr, cons1, prod0,
            wih0, whh0, bih0, bhh0, Abuf, fcred, tid, wave, lane, n16, quad, bbase);
    } else if (layer == 1) {
        run_layer_p<1, true, true, false>(nullptr, r0, r1,
            prod0, cons1, cons2, prod1,
            wih1, whh1, bih1, bhh1, Abuf, fcred, tid, wave, lane, n16, quad, bbase);
    } else {
        run_layer_p<1, true, false, true>(nullptr, r1, nullptr,
            prod1, cons2, nullptr, nullptr,
            wih2, whh2, bih2, bhh2, Abuf, fcred, tid, wave, lane, n16, quad, bbase);
        __syncthreads();
        if (tid < 16) {
            float s = 0.0f;
#pragma unroll 8
            for (int j = 0; j < HID; ++j) s += fcw[j] * fcred[tid * HID + j];
            out[bbase + tid] = s + fcb[0];
        }
    }
}

extern "C" void kernel_launch(void* const* d_in, const int* in_sizes, int n_in,
                              void* d_out, int out_size, void* d_ws, size_t ws_size,
                              hipStream_t stream) {
    (void)in_sizes; (void)n_in; (void)out_size; (void)ws_size;
    const float* x    = (const float*)d_in[0];
    const float* wih0 = (const float*)d_in[1];
    const float* whh0 = (const float*)d_in[2];
    const float* bih0 = (const float*)d_in[3];
    const float* bhh0 = (const float*)d_in[4];
    const float* wih1 = (const float*)d_in[5];
    const float* whh1 = (const float*)d_in[6];
    const float* bih1 = (const float*)d_in[7];
    const float* bhh1 = (const float*)d_in[8];
    const float* wih2 = (const float*)d_in[9];
    const float* whh2 = (const float*)d_in[10];
    const float* bih2 = (const float*)d_in[11];
    const float* bhh2 = (const float*)d_in[12];
    const float* fcw  = (const float*)d_in[13];
    const float* fcb  = (const float*)d_in[14];
    float* out = (float*)d_out;

    // ws layout: flags 64 KB (4 kinds x 64 slices x 256 B; poison 0xAA.. is
    // negative => "not ready", no init needed), ring0 8 MB, ring1 8 MB.
    int* flags = (int*)d_ws;
    u64* ring0 = (u64*)((char*)d_ws + 65536);
    u64* ring1 = ring0 + (size_t)64 * RSLOT * 512;

    lstm3_pipe_kernel<<<dim3(192), dim3(512), 0, stream>>>(
        x, wih0, whh0, bih0, bhh0, wih1, whh1, bih1, bhh1,
        wih2, whh2, bih2, bhh2, fcw, fcb, out, flags, ring0, ring1);
}